// Round 1
// baseline (531.578 us; speedup 1.0000x reference)
//
#include <hip/hip_runtime.h>

#define B_IN   32
#define C_OUT  32
#define KWIN   3
#define PP     4
#define PS     16
#define KB     288          // KWIN*KWIN*B_IN
#define NITER  3
#define EPSL   1e-6f
#define LAM    0.001f
#define OH     12
#define OW     12
#define NB     4
#define NPOS   (NB*OH*OW)   // 576
#define MU_SZ  (NPOS*C_OUT*PS)   // 294912

// ---- weight transpose: w[k][c][j][l] -> wt[k][c][l][j] so a thread's 4 taps
// (j=0..3 at fixed l) become one contiguous float4.
__global__ void transpose_w_kernel(const float* __restrict__ w, float* __restrict__ wt) {
    int idx = blockIdx.x * blockDim.x + threadIdx.x;
    if (idx >= KB * C_OUT * PS) return;
    int j  = idx & 3;
    int l  = (idx >> 2) & 3;
    int kc = idx >> 4;
    wt[idx] = w[kc * 16 + j * 4 + l];
}

template <bool TRANSPOSED>
__device__ __forceinline__ float dot_v(const float4* __restrict__ xpv,
                                       const float* __restrict__ wptr,
                                       int k, int c, int i, int l) {
    float4 xr = xpv[k * 4 + i];            // xp[k][i*4 .. i*4+3]
    if (TRANSPOSED) {
        float4 wr = ((const float4*)wptr)[(k * 32 + c) * 4 + l];
        return xr.x * wr.x + xr.y * wr.y + xr.z * wr.z + xr.w * wr.w;
    } else {
        const float* wb = wptr + (k * 32 + c) * 16 + l;
        return xr.x * wb[0] + xr.y * wb[4] + xr.z * wb[8] + xr.w * wb[12];
    }
}

template <bool TRANSPOSED>
__global__ __launch_bounds__(512)
void emcaps_kernel(const float* __restrict__ x, const float* __restrict__ a,
                   const float* __restrict__ wsrc, const float* __restrict__ beta_u,
                   const float* __restrict__ beta_a, float* __restrict__ out) {
    __shared__ float xp[KB * PS];          // 18 KB: patch poses [k][16]
    __shared__ float a_lds[KB];            // input activations
    __shared__ float rbuf[2][16][33];      // chunk ln_ap / r, padded, double-buffered
    __shared__ float aout_lds[C_OUT];

    const int t  = threadIdx.x;            // 512 threads
    const int c  = t >> 4;                 // output capsule 0..31
    const int e  = t & 15;                 // pose element 0..15
    const int i  = e >> 2;                 // pose row
    const int l  = e & 3;                  // pose col
    const int kg = t >> 5;                 // softmax phase: k-in-chunk 0..15
    const int cc = t & 31;                 // softmax phase: capsule 0..31

    const int pos = blockIdx.x;
    const int bb  = pos / (OH * OW);
    const int rem = pos % (OH * OW);
    const int hh  = rem / OW;
    const int ww  = rem % OW;

    // ---- load 3x3 patch (9 x contiguous 512 floats) as float4, fully coalesced
    const float4* x4  = (const float4*)x;
    float4*       xp4 = (float4*)xp;
    for (int u = t; u < KB * PS / 4; u += 512) {         // 1152 float4
        int pc = u >> 7, r = u & 127;
        int ki = pc / 3, kj = pc % 3;
        long src = (((long)(bb * 14 + hh + ki)) * 14 + (ww + kj)) * 128;
        xp4[u] = x4[src + r];
    }
    if (t < KB) {
        int pc = t >> 5, bi = t & 31;
        int ki = pc / 3, kj = pc % 3;
        a_lds[t] = a[(((bb * 14 + hh + ki)) * 14 + (ww + kj)) * 32 + bi];
    }
    __syncthreads();

    const float bu = beta_u[c];
    const float ba = beta_a[c];
    const float4* xpv = (const float4*)xp;

    float mu = 0.f, inv2s = 0.f, cst = 0.f, aout = 0.f;

    for (int it = 0; it < NITER; ++it) {
        float m1 = 0.f, m2 = 0.f, rs = 0.f;
        if (it == 0) {
            // r[k,c] = a_in[k]/C (same for all c) — no softmax phase
            #pragma unroll 4
            for (int k = 0; k < KB; ++k) {
                float v = dot_v<TRANSPOSED>(xpv, wsrc, k, c, i, l);
                float r = a_lds[k] * (1.0f / C_OUT);
                m1 += r * v;
                m2 += r * v * v;
                rs += r;
            }
        } else {
            int p = 0;
            for (int ch = 0; ch < KB / 16; ++ch) {
                const int base = ch * 16;
                float vbuf[16];
                // Phase A: v + ln-term, reduce over e (16 lanes), write ln_ap chunk
                #pragma unroll
                for (int kk = 0; kk < 16; ++kk) {
                    int k = base + kk;
                    float v = dot_v<TRANSPOSED>(xpv, wsrc, k, c, i, l);
                    vbuf[kk] = v;
                    float d = v - mu;
                    float term = -d * d * inv2s;
                    term += __shfl_xor(term, 1);
                    term += __shfl_xor(term, 2);
                    term += __shfl_xor(term, 4);
                    term += __shfl_xor(term, 8);
                    if (e == 0) rbuf[p][kk][c] = term + cst;
                }
                __syncthreads();
                // Phase B: softmax over c (32 lanes per k), r = softmax * a_out
                {
                    float ln = rbuf[p][kg][cc];
                    float mx = ln;
                    mx = fmaxf(mx, __shfl_xor(mx, 16));
                    mx = fmaxf(mx, __shfl_xor(mx, 8));
                    mx = fmaxf(mx, __shfl_xor(mx, 4));
                    mx = fmaxf(mx, __shfl_xor(mx, 2));
                    mx = fmaxf(mx, __shfl_xor(mx, 1));
                    float pex = __expf(ln - mx);
                    float sm = pex;
                    sm += __shfl_xor(sm, 16);
                    sm += __shfl_xor(sm, 8);
                    sm += __shfl_xor(sm, 4);
                    sm += __shfl_xor(sm, 2);
                    sm += __shfl_xor(sm, 1);
                    rbuf[p][kg][cc] = (pex / sm) * aout_lds[cc];
                }
                __syncthreads();
                // Phase C: un-normalized moments (linear in r — divide later)
                #pragma unroll
                for (int kk = 0; kk < 16; ++kk) {
                    float r = rbuf[p][kk][c];
                    float v = vbuf[kk];
                    m1 += r * v;
                    m2 += r * v * v;
                    rs += r;
                }
                p ^= 1;
            }
        }
        // ---- M-step finalize (per-thread; mu/sigma live in registers)
        float inv = 1.0f / (rs + EPSL);
        mu = m1 * inv;
        float s   = rs * inv;                 // sum of coeff
        float sig = m2 * inv - mu * mu * (2.0f - s) + EPSL;
        float hl  = 0.5f * __logf(sig);       // Σ_e 0.5 log σ² via butterfly
        hl += __shfl_xor(hl, 1);
        hl += __shfl_xor(hl, 2);
        hl += __shfl_xor(hl, 4);
        hl += __shfl_xor(hl, 8);
        inv2s = 0.5f / sig;
        float costsum = (16.0f * bu + hl) * rs;
        aout = 1.0f / (1.0f + __expf(-LAM * (ba - costsum)));
        cst  = __logf(aout) - hl;             // per-c constant for next E-step
        if (e == 0) aout_lds[c] = aout;
        // no barrier needed: next read of aout_lds is after chunk-0 Phase A barrier
    }

    // ---- outputs: mu then a_out, concatenated flat
    out[pos * 512 + t] = mu;                  // t == c*16+e -> contiguous
    if (e == 0) out[MU_SZ + pos * 32 + c] = aout;
}

extern "C" void kernel_launch(void* const* d_in, const int* in_sizes, int n_in,
                              void* d_out, int out_size, void* d_ws, size_t ws_size,
                              hipStream_t stream) {
    const float* x  = (const float*)d_in[0];
    const float* a  = (const float*)d_in[1];
    const float* w  = (const float*)d_in[2];
    const float* bu = (const float*)d_in[3];
    const float* ba = (const float*)d_in[4];
    float* out = (float*)d_out;

    const size_t wt_bytes = (size_t)KB * C_OUT * PS * sizeof(float);  // 576 KB
    if (ws_size >= wt_bytes) {
        float* wt = (float*)d_ws;
        transpose_w_kernel<<<(KB * C_OUT * PS + 255) / 256, 256, 0, stream>>>(w, wt);
        emcaps_kernel<true><<<NPOS, 512, 0, stream>>>(x, a, wt, bu, ba, out);
    } else {
        emcaps_kernel<false><<<NPOS, 512, 0, stream>>>(x, a, w, bu, ba, out);
    }
}

// Round 2
// 228.998 us; speedup vs baseline: 2.3213x; 2.3213x over previous
//
#include <hip/hip_runtime.h>

#define C_OUT  32
#define PS     16
#define KB     288          // 3*3*32 input capsules per patch
#define NITER  3
#define EPSL   1e-6f
#define LAM    0.001f
#define OH     12
#define OW     12
#define NPOS   576          // 4*12*12
#define MU_SZ  (NPOS*C_OUT*PS)
#define NG     16           // k-groups (one per thread-row)
#define KPG    (KB/NG)      // 18 k's per thread

// v[k,c,i,l] = sum_j xp[k,i,j] * w[k,c,j,l]  — full 4x4 matrix per (k,c) in registers.
__device__ __forceinline__ void compute_v(const float* __restrict__ xp,
                                          const float* __restrict__ w,
                                          int k, int c, float* __restrict__ va) {
    const float4* xk = (const float4*)(xp + (k << 4));
    float4 x0 = xk[0], x1 = xk[1], x2 = xk[2], x3 = xk[3];   // row i over j
    const float4* wr = (const float4*)(w + (((k << 5) + c) << 4));
    float4 w0 = wr[0], w1 = wr[1], w2 = wr[2], w3 = wr[3];   // row j over l
#define VROW(i, xi) \
    va[4*i+0] = fmaf(xi.x, w0.x, fmaf(xi.y, w1.x, fmaf(xi.z, w2.x, xi.w * w3.x))); \
    va[4*i+1] = fmaf(xi.x, w0.y, fmaf(xi.y, w1.y, fmaf(xi.z, w2.y, xi.w * w3.y))); \
    va[4*i+2] = fmaf(xi.x, w0.z, fmaf(xi.y, w1.z, fmaf(xi.z, w2.z, xi.w * w3.z))); \
    va[4*i+3] = fmaf(xi.x, w0.w, fmaf(xi.y, w1.w, fmaf(xi.z, w2.w, xi.w * w3.w)));
    VROW(0, x0) VROW(1, x1) VROW(2, x2) VROW(3, x3)
#undef VROW
}

__global__ __launch_bounds__(512, 4)
void emcaps_kernel(const float* __restrict__ x, const float* __restrict__ a,
                   const float* __restrict__ w, const float* __restrict__ beta_u,
                   const float* __restrict__ beta_a, float* __restrict__ out) {
    __shared__ __align__(16) float xp[KB * PS];   // 18 KB patch poses [k][16]
    __shared__ float a_lds[KB];                   // input activations
    __shared__ float m1p[8][32][16];              // 16 KB partial m1 [gpair][c][e^ (c&15)]
    __shared__ float m2p[8][32][16];              // 16 KB partial m2
    __shared__ float rsp[8][32];                  // partial r_sum
    __shared__ float mu_s[32][16];                // mu   [c][e ^ (c&15)]
    __shared__ float is_s[32][16];                // 0.5/sigma^2, same swizzle
    __shared__ float cst_s[32];                   // log(a_out) - sum_e 0.5 log sigma^2
    __shared__ float ao_s[32];                    // a_out

    const int t  = threadIdx.x;       // 512 threads
    const int g  = t >> 5;            // k-group 0..15  (E-step view)
    const int c  = t & 31;            // output capsule (E-step view)
    const int oc = t >> 4;            // capsule 0..31  (M-step view)
    const int oe = t & 15;            // pose elem      (M-step view)

    const int pos = blockIdx.x;
    const int bb  = pos / (OH * OW);
    const int rem = pos % (OH * OW);
    const int hh  = rem / OW;
    const int ww  = rem % OW;

    // ---- stage 3x3 patch into LDS (9 contiguous 2 KB rows, coalesced float4)
    const float4* x4  = (const float4*)x;
    float4*       xp4 = (float4*)xp;
    for (int u = t; u < KB * PS / 4; u += 512) {
        int pc = u >> 7, r = u & 127;
        int ki = pc / 3, kj = pc % 3;
        long src = (((long)(bb * 14 + hh + ki)) * 14 + (ww + kj)) * 128;
        xp4[u] = x4[src + r];
    }
    if (t < KB) {
        int pc = t >> 5, bi = t & 31;
        int ki = pc / 3, kj = pc % 3;
        a_lds[t] = a[(((bb * 14 + hh + ki)) * 14 + (ww + kj)) * 32 + bi];
    }
    __syncthreads();

    const float buC = beta_u[oc];     // M-step view constants
    const float baC = beta_a[oc];

    float muR[16], isR[16];           // E-step per-c state (registers)
    float cstC = 0.f, aoC = 0.f;

    for (int it = 0; it < NITER; ++it) {
        float m1[16], m2[16], rs = 0.f;
        #pragma unroll
        for (int e = 0; e < 16; ++e) { m1[e] = 0.f; m2[e] = 0.f; }

        if (it == 0) {
            #pragma unroll 2
            for (int kk = 0; kk < KPG; ++kk) {
                int k = g * KPG + kk;
                float va[16];
                compute_v(xp, w, k, c, va);
                float r = a_lds[k] * (1.0f / C_OUT);
                rs += r;
                #pragma unroll
                for (int e = 0; e < 16; ++e) {
                    float rv = r * va[e];
                    m1[e] += rv;
                    m2[e] = fmaf(rv, va[e], m2[e]);
                }
            }
        } else {
            #pragma unroll 2
            for (int kk = 0; kk < KPG; ++kk) {
                int k = g * KPG + kk;
                float va[16];
                compute_v(xp, w, k, c, va);
                // ln-term: fully lane-local (no shuffles)
                float acc = 0.f;
                #pragma unroll
                for (int e = 0; e < 16; ++e) {
                    float d = va[e] - muR[e];
                    acc = fmaf(d * d, isR[e], acc);
                }
                float ln = cstC - acc;
                // softmax over c: 32-lane butterfly (lane bits 0..4)
                float mx = ln;
                mx = fmaxf(mx, __shfl_xor(mx, 16));
                mx = fmaxf(mx, __shfl_xor(mx, 8));
                mx = fmaxf(mx, __shfl_xor(mx, 4));
                mx = fmaxf(mx, __shfl_xor(mx, 2));
                mx = fmaxf(mx, __shfl_xor(mx, 1));
                float p = __expf(ln - mx);
                float sm = p;
                sm += __shfl_xor(sm, 16);
                sm += __shfl_xor(sm, 8);
                sm += __shfl_xor(sm, 4);
                sm += __shfl_xor(sm, 2);
                sm += __shfl_xor(sm, 1);
                float r = (p / sm) * aoC;
                rs += r;
                #pragma unroll
                for (int e = 0; e < 16; ++e) {
                    float rv = r * va[e];
                    m1[e] += rv;
                    m2[e] = fmaf(rv, va[e], m2[e]);
                }
            }
        }

        // ---- reduce over g: pair-reduce in-wave, then swizzled LDS tree
        rs += __shfl_xor(rs, 32);
        #pragma unroll
        for (int e = 0; e < 16; ++e) m1[e] += __shfl_xor(m1[e], 32);
        #pragma unroll
        for (int e = 0; e < 16; ++e) m2[e] += __shfl_xor(m2[e], 32);
        if ((g & 1) == 0) {
            int gp = g >> 1;
            #pragma unroll
            for (int e = 0; e < 16; ++e) m1p[gp][c][e ^ (c & 15)] = m1[e];
            #pragma unroll
            for (int e = 0; e < 16; ++e) m2p[gp][c][e ^ (c & 15)] = m2[e];
            rsp[gp][c] = rs;
        }
        __syncthreads();

        // ---- M-step in (oc, oe) view
        float M1 = 0.f, M2 = 0.f, RS = 0.f;
        #pragma unroll
        for (int gp = 0; gp < 8; ++gp) M1 += m1p[gp][oc][oe ^ (oc & 15)];
        #pragma unroll
        for (int gp = 0; gp < 8; ++gp) M2 += m2p[gp][oc][oe ^ (oc & 15)];
        #pragma unroll
        for (int gp = 0; gp < 8; ++gp) RS += rsp[gp][oc];

        float inv = 1.0f / (RS + EPSL);
        float muv = M1 * inv;
        float s   = RS * inv;
        float sig = fmaf(-muv * muv, (2.0f - s), M2 * inv) + EPSL;
        float hl  = 0.5f * __logf(sig);
        hl += __shfl_xor(hl, 1);
        hl += __shfl_xor(hl, 2);
        hl += __shfl_xor(hl, 4);
        hl += __shfl_xor(hl, 8);
        float cost = RS * fmaf(16.0f, buC, hl);
        float ao   = 1.0f / (1.0f + __expf(-LAM * (baC - cost)));

        if (it == NITER - 1) {
            out[pos * 512 + t] = muv;                    // t == oc*16+oe
            if (oe == 0) out[MU_SZ + pos * 32 + oc] = ao;
        } else {
            mu_s[oc][oe ^ (oc & 15)] = muv;
            is_s[oc][oe ^ (oc & 15)] = 0.5f / sig;
            if (oe == 0) { cst_s[oc] = __logf(ao) - hl; ao_s[oc] = ao; }
            __syncthreads();
            // back in (g,c) view: pull next-iteration E-state into registers
            #pragma unroll
            for (int e = 0; e < 16; ++e) muR[e] = mu_s[c][e ^ (c & 15)];
            #pragma unroll
            for (int e = 0; e < 16; ++e) isR[e] = is_s[c][e ^ (c & 15)];
            cstC = cst_s[c];
            aoC  = ao_s[c];
        }
    }
}

extern "C" void kernel_launch(void* const* d_in, const int* in_sizes, int n_in,
                              void* d_out, int out_size, void* d_ws, size_t ws_size,
                              hipStream_t stream) {
    const float* x  = (const float*)d_in[0];
    const float* a  = (const float*)d_in[1];
    const float* w  = (const float*)d_in[2];
    const float* bu = (const float*)d_in[3];
    const float* ba = (const float*)d_in[4];
    float* out = (float*)d_out;
    emcaps_kernel<<<NPOS, 512, 0, stream>>>(x, a, w, bu, ba, out);
}